// Round 1
// baseline (2961.881 us; speedup 1.0000x reference)
//
#include <hip/hip_runtime.h>
#include <math.h>

#define NH 16
#define HD 64
#define DIM 1024
#define QKV_DIM 3072
#define MAXLEN 2048

// hardcoded problem constants (fixed by reference setup)
__device__ __constant__ int g_cu[5]  = {0, 2048, 3584, 4608, 5120};
__device__ __constant__ int g_seq[4] = {2048, 1536, 1024, 512};

// ---------------------------------------------------------------------------
// GEMM: C[M][N] = A[M][K] * B[N][K]^T   (both A,B row-major, K-contiguous)
// 128x128 tile, BK=16, 256 threads, 8x8 per thread, fp32.
// Assumes M%128==0, N%128==0, K%16==0 (true for all calls here).
// ---------------------------------------------------------------------------
__global__ __launch_bounds__(256) void gemm_abt(const float* __restrict__ A,
                                                const float* __restrict__ B,
                                                float* __restrict__ C,
                                                int M, int N, int K) {
    constexpr int BM = 128, BN = 128, BK = 16;
    __shared__ float As[BK][BM + 4];
    __shared__ float Bs[BK][BN + 4];

    const int tid = threadIdx.x;
    const int bm = blockIdx.y * BM;
    const int bn = blockIdx.x * BN;
    const int ty = tid / 16;   // 0..15 -> row group
    const int tx = tid % 16;   // 0..15 -> col group

    float acc[8][8] = {};

    for (int k0 = 0; k0 < K; k0 += BK) {
        // Load A tile: 128x16 floats = 512 float4 items, 2 per thread.
#pragma unroll
        for (int it = 0; it < 2; ++it) {
            int item = tid + it * 256;
            int r = item >> 2;            // 0..127
            int c4 = item & 3;            // 0..3  (float4 along K)
            float4 v = *(const float4*)&A[(size_t)(bm + r) * K + k0 + c4 * 4];
            As[c4 * 4 + 0][r] = v.x;
            As[c4 * 4 + 1][r] = v.y;
            As[c4 * 4 + 2][r] = v.z;
            As[c4 * 4 + 3][r] = v.w;
        }
#pragma unroll
        for (int it = 0; it < 2; ++it) {
            int item = tid + it * 256;
            int r = item >> 2;
            int c4 = item & 3;
            float4 v = *(const float4*)&B[(size_t)(bn + r) * K + k0 + c4 * 4];
            Bs[c4 * 4 + 0][r] = v.x;
            Bs[c4 * 4 + 1][r] = v.y;
            Bs[c4 * 4 + 2][r] = v.z;
            Bs[c4 * 4 + 3][r] = v.w;
        }
        __syncthreads();

#pragma unroll
        for (int k = 0; k < BK; ++k) {
            float a[8], b[8];
            *(float4*)&a[0] = *(const float4*)&As[k][ty * 8 + 0];
            *(float4*)&a[4] = *(const float4*)&As[k][ty * 8 + 4];
            *(float4*)&b[0] = *(const float4*)&Bs[k][tx * 8 + 0];
            *(float4*)&b[4] = *(const float4*)&Bs[k][tx * 8 + 4];
#pragma unroll
            for (int i = 0; i < 8; ++i)
#pragma unroll
                for (int j = 0; j < 8; ++j) acc[i][j] = fmaf(a[i], b[j], acc[i][j]);
        }
        __syncthreads();
    }

#pragma unroll
    for (int i = 0; i < 8; ++i) {
#pragma unroll
        for (int j = 0; j < 8; j += 4) {
            float4 v = {acc[i][j], acc[i][j + 1], acc[i][j + 2], acc[i][j + 3]};
            *(float4*)&C[(size_t)(bm + ty * 8 + i) * N + bn + tx * 8 + j] = v;
        }
    }
}

// ---------------------------------------------------------------------------
// RoPE in place on q and k halves of the unpadded qkv buffer.
// One thread per (row, head, pair j). ROT_DIM == HD == 64, d2 = 32.
// ---------------------------------------------------------------------------
__global__ __launch_bounds__(256) void rope_kernel(float* __restrict__ qkv, int total) {
    int id = blockIdx.x * blockDim.x + threadIdx.x;
    int nitems = total * NH * 32;
    if (id >= nitems) return;
    int j = id & 31;
    int h = (id >> 5) & (NH - 1);
    int row = id >> 9;  // / (32*NH)

    int b = 0;
    while (row >= g_cu[b + 1]) b++;
    int pos = row - g_cu[b];

    float inv_freq = powf(10000.0f, -(float)(2 * j) / 64.0f);
    float fr = (float)pos * inv_freq;
    float c = cosf(fr), s = sinf(fr);

    float* base = qkv + (size_t)row * QKV_DIM + h * HD;
#pragma unroll
    for (int part = 0; part < 2; ++part) {  // q then k
        float* p = base + part * DIM;
        float x1 = p[j];
        float x2 = p[j + 32];
        p[j] = x1 * c - x2 * s;
        p[j + 32] = x2 * c + x1 * s;
    }
}

// ---------------------------------------------------------------------------
// Attention: one thread = one query row (one head). 128 threads/block = one
// 128-query tile of one (batch, head). Keys streamed through LDS in tiles of
// 32. Online softmax; padded keys contribute (MAXLEN-L)*exp(-m) to the
// denominator only (their v rows are zero).
// ---------------------------------------------------------------------------
__global__ __launch_bounds__(128) void attn_kernel(const float* __restrict__ qkv,
                                                   float* __restrict__ attn) {
    __shared__ float Ks[32][64];
    __shared__ float Vs[32][64];

    // blockIdx.x in [0,40): per-batch tile counts {16,12,8,4}, prefix below.
    const int tiles_pref[5] = {0, 16, 28, 36, 40};
    int t = blockIdx.x;
    int b = 0;
    while (t >= tiles_pref[b + 1]) b++;
    const int qstart = (t - tiles_pref[b]) * 128;
    const int h = blockIdx.y;
    const int L = g_seq[b];
    const int base = g_cu[b];
    const int tidx = threadIdx.x;
    const int qpos = qstart + tidx;  // always < L (L % 128 == 0)

    const float scale = 0.125f;  // 1/sqrt(64)
    const float* qrow = qkv + (size_t)(base + qpos) * QKV_DIM + h * HD;
    float q[64];
#pragma unroll
    for (int i = 0; i < 16; ++i) {
        float4 v = *(const float4*)&qrow[i * 4];
        q[i * 4 + 0] = v.x * scale;
        q[i * 4 + 1] = v.y * scale;
        q[i * 4 + 2] = v.z * scale;
        q[i * 4 + 3] = v.w * scale;
    }

    float acc[64] = {};
    float m = -1e30f, d = 0.0f;

    for (int k0 = 0; k0 < L; k0 += 32) {
        // load 32x64 K and V tiles: 512 float4 items each, 4 per thread
#pragma unroll
        for (int it = 0; it < 4; ++it) {
            int item = tidx + it * 128;
            int r = item >> 4;       // 0..31
            int c4 = item & 15;      // 0..15
            const float* src = qkv + (size_t)(base + k0 + r) * QKV_DIM + DIM + h * HD + c4 * 4;
            *(float4*)&Ks[r][c4 * 4] = *(const float4*)src;
            *(float4*)&Vs[r][c4 * 4] = *(const float4*)(src + DIM);
        }
        __syncthreads();

        float s[32];
        float tmax = -1e30f;
#pragma unroll
        for (int kk = 0; kk < 32; ++kk) {
            float dot = 0.0f;
#pragma unroll
            for (int i = 0; i < 16; ++i) {
                float4 kv = *(const float4*)&Ks[kk][i * 4];
                dot = fmaf(q[i * 4 + 0], kv.x, dot);
                dot = fmaf(q[i * 4 + 1], kv.y, dot);
                dot = fmaf(q[i * 4 + 2], kv.z, dot);
                dot = fmaf(q[i * 4 + 3], kv.w, dot);
            }
            s[kk] = dot;
            tmax = fmaxf(tmax, dot);
        }

        float mnew = fmaxf(m, tmax);
        float corr = __expf(m - mnew);
        d *= corr;
#pragma unroll
        for (int i = 0; i < 64; ++i) acc[i] *= corr;

#pragma unroll
        for (int kk = 0; kk < 32; ++kk) {
            float p = __expf(s[kk] - mnew);
            d += p;
#pragma unroll
            for (int i = 0; i < 16; ++i) {
                float4 vv = *(const float4*)&Vs[kk][i * 4];
                acc[i * 4 + 0] = fmaf(p, vv.x, acc[i * 4 + 0]);
                acc[i * 4 + 1] = fmaf(p, vv.y, acc[i * 4 + 1]);
                acc[i * 4 + 2] = fmaf(p, vv.z, acc[i * 4 + 2]);
                acc[i * 4 + 3] = fmaf(p, vv.w, acc[i * 4 + 3]);
            }
        }
        m = mnew;
        __syncthreads();
    }

    // padded keys: score 0, v 0 -> denominator only
    int npad = MAXLEN - L;
    if (npad) d += (float)npad * __expf(0.0f - m);

    float inv = 1.0f / d;
    float* orow = attn + (size_t)(base + qpos) * DIM + h * HD;
#pragma unroll
    for (int i = 0; i < 16; ++i) {
        float4 v = {acc[i * 4 + 0] * inv, acc[i * 4 + 1] * inv,
                    acc[i * 4 + 2] * inv, acc[i * 4 + 3] * inv};
        *(float4*)&orow[i * 4] = v;
    }
}

// ---------------------------------------------------------------------------
extern "C" void kernel_launch(void* const* d_in, const int* in_sizes, int n_in,
                              void* d_out, int out_size, void* d_ws, size_t ws_size,
                              hipStream_t stream) {
    const float* hidden = (const float*)d_in[0];
    const float* Wqkv = (const float*)d_in[1];
    const float* Wo = (const float*)d_in[2];
    float* out = (float*)d_out;

    const int total = in_sizes[0] / DIM;  // 5120

    float* qkv = (float*)d_ws;                        // total * 3072
    float* attn = qkv + (size_t)total * QKV_DIM;      // total * 1024

    // 1) qkv = hidden @ Wqkv^T   (5120 x 3072, K=1024)
    gemm_abt<<<dim3(QKV_DIM / 128, total / 128), 256, 0, stream>>>(
        hidden, Wqkv, qkv, total, QKV_DIM, DIM);

    // 2) RoPE in place on q,k
    int nitems = total * NH * 32;
    rope_kernel<<<(nitems + 255) / 256, 256, 0, stream>>>(qkv, total);

    // 3) attention -> attn buffer
    attn_kernel<<<dim3(40, NH), 128, 0, stream>>>(qkv, attn);

    // 4) out = attn @ Wo^T       (5120 x 1024, K=1024)
    gemm_abt<<<dim3(DIM / 128, total / 128), 256, 0, stream>>>(
        attn, Wo, out, total, DIM, DIM);
}

// Round 3
// 1641.169 us; speedup vs baseline: 1.8047x; 1.8047x over previous
//
#include <hip/hip_runtime.h>
#include <math.h>

#define NH 16
#define HD 64
#define DIM 1024
#define QKV_DIM 3072
#define MAXLEN 2048

// hardcoded problem constants (fixed by reference setup)
__device__ __constant__ int g_cu[5]  = {0, 2048, 3584, 4608, 5120};
__device__ __constant__ int g_seq[4] = {2048, 1536, 1024, 512};

// ---------------------------------------------------------------------------
// GEMM: C[M][N] = A[M][K] * B[N][K]^T   (both A,B row-major, K-contiguous)
// 128x128 tile, BK=16, 256 threads, 8x8 per thread, fp32.
// Assumes M%128==0, N%128==0, K%16==0 (true for all calls here).
// ---------------------------------------------------------------------------
__global__ __launch_bounds__(256) void gemm_abt(const float* __restrict__ A,
                                                const float* __restrict__ B,
                                                float* __restrict__ C,
                                                int M, int N, int K) {
    constexpr int BM = 128, BN = 128, BK = 16;
    __shared__ float As[BK][BM + 4];
    __shared__ float Bs[BK][BN + 4];

    const int tid = threadIdx.x;
    const int bm = blockIdx.y * BM;
    const int bn = blockIdx.x * BN;
    const int ty = tid / 16;   // 0..15 -> row group
    const int tx = tid % 16;   // 0..15 -> col group

    float acc[8][8] = {};

    for (int k0 = 0; k0 < K; k0 += BK) {
        // Load A tile: 128x16 floats = 512 float4 items, 2 per thread.
#pragma unroll
        for (int it = 0; it < 2; ++it) {
            int item = tid + it * 256;
            int r = item >> 2;            // 0..127
            int c4 = item & 3;            // 0..3  (float4 along K)
            float4 v = *(const float4*)&A[(size_t)(bm + r) * K + k0 + c4 * 4];
            As[c4 * 4 + 0][r] = v.x;
            As[c4 * 4 + 1][r] = v.y;
            As[c4 * 4 + 2][r] = v.z;
            As[c4 * 4 + 3][r] = v.w;
        }
#pragma unroll
        for (int it = 0; it < 2; ++it) {
            int item = tid + it * 256;
            int r = item >> 2;
            int c4 = item & 3;
            float4 v = *(const float4*)&B[(size_t)(bn + r) * K + k0 + c4 * 4];
            Bs[c4 * 4 + 0][r] = v.x;
            Bs[c4 * 4 + 1][r] = v.y;
            Bs[c4 * 4 + 2][r] = v.z;
            Bs[c4 * 4 + 3][r] = v.w;
        }
        __syncthreads();

#pragma unroll
        for (int k = 0; k < BK; ++k) {
            float a[8], b[8];
            *(float4*)&a[0] = *(const float4*)&As[k][ty * 8 + 0];
            *(float4*)&a[4] = *(const float4*)&As[k][ty * 8 + 4];
            *(float4*)&b[0] = *(const float4*)&Bs[k][tx * 8 + 0];
            *(float4*)&b[4] = *(const float4*)&Bs[k][tx * 8 + 4];
#pragma unroll
            for (int i = 0; i < 8; ++i)
#pragma unroll
                for (int j = 0; j < 8; ++j) acc[i][j] = fmaf(a[i], b[j], acc[i][j]);
        }
        __syncthreads();
    }

#pragma unroll
    for (int i = 0; i < 8; ++i) {
#pragma unroll
        for (int j = 0; j < 8; j += 4) {
            float4 v = {acc[i][j], acc[i][j + 1], acc[i][j + 2], acc[i][j + 3]};
            *(float4*)&C[(size_t)(bm + ty * 8 + i) * N + bn + tx * 8 + j] = v;
        }
    }
}

// ---------------------------------------------------------------------------
// RoPE in place on q and k halves of the unpadded qkv buffer.
// One thread per (row, head, pair j). ROT_DIM == HD == 64, d2 = 32.
// ---------------------------------------------------------------------------
__global__ __launch_bounds__(256) void rope_kernel(float* __restrict__ qkv, int total) {
    int id = blockIdx.x * blockDim.x + threadIdx.x;
    int nitems = total * NH * 32;
    if (id >= nitems) return;
    int j = id & 31;
    int h = (id >> 5) & (NH - 1);
    int row = id >> 9;  // / (32*NH)

    int b = 0;
    while (row >= g_cu[b + 1]) b++;
    int pos = row - g_cu[b];

    float inv_freq = powf(10000.0f, -(float)(2 * j) / 64.0f);
    float fr = (float)pos * inv_freq;
    float c = cosf(fr), s = sinf(fr);

    float* base = qkv + (size_t)row * QKV_DIM + h * HD;
#pragma unroll
    for (int part = 0; part < 2; ++part) {  // q then k
        float* p = base + part * DIM;
        float x1 = p[j];
        float x2 = p[j + 32];
        p[j] = x1 * c - x2 * s;
        p[j + 32] = x2 * c + x1 * s;
    }
}

// ---------------------------------------------------------------------------
// Attention v2: 4 lanes per query row, each lane owns 16 of the 64 head dims.
// q[16] + acc[16] + s[32] per lane -> no VGPR spill (the v1 killer: 116 VGPRs
// with 160+ live floats -> scratch). Block = 256 threads = 64 query rows of
// one (batch, head). K/V streamed through LDS in 32-key tiles. QK partial
// dots combined across the 4-lane quad via shfl_xor; softmax scalars computed
// redundantly per lane. Padded keys (score 0, v 0) contribute
// (MAXLEN-L)*exp(-m) to the denominator only.
// ---------------------------------------------------------------------------
__global__ __launch_bounds__(256) void attn_kernel(const float* __restrict__ qkv,
                                                   float* __restrict__ attn) {
    __shared__ float Ks[32][64];
    __shared__ float Vs[32][64];

    // blockIdx.x in [0,80): per-batch 64-row tile counts {32,24,16,8}.
    const int tiles_pref[5] = {0, 32, 56, 72, 80};
    int t = blockIdx.x;
    int b = 0;
    while (t >= tiles_pref[b + 1]) b++;
    const int qstart = (t - tiles_pref[b]) * 64;
    const int h = blockIdx.y;
    const int L = g_seq[b];
    const int base = g_cu[b];
    const int tid = threadIdx.x;
    const int row = qstart + (tid >> 2);  // query row within batch, < L
    const int quad = tid & 3;             // which 16-dim quarter this lane owns

    const float scale = 0.125f;  // 1/sqrt(64)
    const float* qrow = qkv + (size_t)(base + row) * QKV_DIM + h * HD + quad * 16;
    float q[16];
#pragma unroll
    for (int i = 0; i < 4; ++i) {
        float4 v = *(const float4*)&qrow[i * 4];
        q[i * 4 + 0] = v.x * scale;
        q[i * 4 + 1] = v.y * scale;
        q[i * 4 + 2] = v.z * scale;
        q[i * 4 + 3] = v.w * scale;
    }

    float acc[16] = {};
    float m = -1e30f, d = 0.0f;

    for (int k0 = 0; k0 < L; k0 += 32) {
        // load 32x64 K and V tiles: 512 float4 items each, 2 per thread each
#pragma unroll
        for (int it = 0; it < 2; ++it) {
            int item = tid + it * 256;
            int r = item >> 4;       // 0..31
            int c4 = item & 15;      // 0..15
            const float* src = qkv + (size_t)(base + k0 + r) * QKV_DIM + DIM + h * HD + c4 * 4;
            *(float4*)&Ks[r][c4 * 4] = *(const float4*)src;
            *(float4*)&Vs[r][c4 * 4] = *(const float4*)(src + DIM);
        }
        __syncthreads();

        float s[32];
        float tmax = -1e30f;
#pragma unroll
        for (int kk = 0; kk < 32; ++kk) {
            float dot = 0.0f;
            const float* kr = &Ks[kk][quad * 16];
#pragma unroll
            for (int i = 0; i < 4; ++i) {
                float4 kv = *(const float4*)&kr[i * 4];
                dot = fmaf(q[i * 4 + 0], kv.x, dot);
                dot = fmaf(q[i * 4 + 1], kv.y, dot);
                dot = fmaf(q[i * 4 + 2], kv.z, dot);
                dot = fmaf(q[i * 4 + 3], kv.w, dot);
            }
            // combine the 4 partial dots within the lane-quad
            dot += __shfl_xor(dot, 1);
            dot += __shfl_xor(dot, 2);
            s[kk] = dot;
            tmax = fmaxf(tmax, dot);
        }

        float mnew = fmaxf(m, tmax);
        float corr = __expf(m - mnew);
        d *= corr;
#pragma unroll
        for (int i = 0; i < 16; ++i) acc[i] *= corr;

#pragma unroll
        for (int kk = 0; kk < 32; ++kk) {
            float p = __expf(s[kk] - mnew);
            d += p;
            const float* vr = &Vs[kk][quad * 16];
#pragma unroll
            for (int i = 0; i < 4; ++i) {
                float4 vv = *(const float4*)&vr[i * 4];
                acc[i * 4 + 0] = fmaf(p, vv.x, acc[i * 4 + 0]);
                acc[i * 4 + 1] = fmaf(p, vv.y, acc[i * 4 + 1]);
                acc[i * 4 + 2] = fmaf(p, vv.z, acc[i * 4 + 2]);
                acc[i * 4 + 3] = fmaf(p, vv.w, acc[i * 4 + 3]);
            }
        }
        m = mnew;
        __syncthreads();
    }

    // padded keys: score 0, v 0 -> denominator only
    int npad = MAXLEN - L;
    if (npad) d += (float)npad * __expf(0.0f - m);

    float inv = 1.0f / d;
    float* orow = attn + (size_t)(base + row) * DIM + h * HD + quad * 16;
#pragma unroll
    for (int i = 0; i < 4; ++i) {
        float4 v = {acc[i * 4 + 0] * inv, acc[i * 4 + 1] * inv,
                    acc[i * 4 + 2] * inv, acc[i * 4 + 3] * inv};
        *(float4*)&orow[i * 4] = v;
    }
}

// ---------------------------------------------------------------------------
extern "C" void kernel_launch(void* const* d_in, const int* in_sizes, int n_in,
                              void* d_out, int out_size, void* d_ws, size_t ws_size,
                              hipStream_t stream) {
    const float* hidden = (const float*)d_in[0];
    const float* Wqkv = (const float*)d_in[1];
    const float* Wo = (const float*)d_in[2];
    float* out = (float*)d_out;

    const int total = in_sizes[0] / DIM;  // 5120

    float* qkv = (float*)d_ws;                        // total * 3072
    float* attn = qkv + (size_t)total * QKV_DIM;      // total * 1024

    // 1) qkv = hidden @ Wqkv^T   (5120 x 3072, K=1024)
    gemm_abt<<<dim3(QKV_DIM / 128, total / 128), 256, 0, stream>>>(
        hidden, Wqkv, qkv, total, QKV_DIM, DIM);

    // 2) RoPE in place on q,k
    int nitems = total * NH * 32;
    rope_kernel<<<(nitems + 255) / 256, 256, 0, stream>>>(qkv, total);

    // 3) attention -> attn buffer
    attn_kernel<<<dim3(80, NH), 256, 0, stream>>>(qkv, attn);

    // 4) out = attn @ Wo^T       (5120 x 1024, K=1024)
    gemm_abt<<<dim3(DIM / 128, total / 128), 256, 0, stream>>>(
        attn, Wo, out, total, DIM, DIM);
}